// Round 1
// baseline (1363.693 us; speedup 1.0000x reference)
//
#include <hip/hip_runtime.h>
#include <math.h>

#define B_ 8
#define C_ 256
#define H_ 128
#define W_ 128
#define HW_ (H_*W_)                 // 16384
#define PLANE ((size_t)C_*HW_)      // 4194304 elems per batch image

// ---------------------------------------------------------------------------
// conv1x1: Y[b][co][p] = sum_ci Wt[co][ci] * X[b][ci][p] + bias[co] (+resid)
// GEMM per batch: M=C(256) x N=HW(16384) x K=C(256)
// Tile: BM=64, BN=128, BK=16; 256 threads; 4x8 register tile per thread.
// ---------------------------------------------------------------------------
template<bool RESID>
__global__ __launch_bounds__(256)
void conv1x1_k(const float* __restrict__ X, const float* __restrict__ Wt,
               const float* __restrict__ bias, const float* __restrict__ resid,
               float* __restrict__ Y)
{
    constexpr int BM = 64, BN = 128, BK = 16;
    __shared__ float Wl[BK][BM + 4];   // [k][m], padded so float4 reads stay 16B-aligned
    __shared__ float Xl[BK][BN];       // [k][n]

    const int b   = blockIdx.z;
    const int cm0 = blockIdx.y * BM;
    const int pn0 = blockIdx.x * BN;
    const int t   = threadIdx.x;
    const int tx  = t & 15;            // n-tile index (8 cols)
    const int ty  = t >> 4;            // m-tile index (4 rows)
    const float* Xb = X + (size_t)b * PLANE;

    float acc[4][8];
#pragma unroll
    for (int i = 0; i < 4; ++i)
#pragma unroll
        for (int j = 0; j < 8; ++j) acc[i][j] = 0.f;

    for (int k0 = 0; k0 < C_; k0 += BK) {
        // W tile: Wl[kk][m] = Wt[cm0+m][k0+kk]
        {
            const int m  = t >> 2;
            const int kk = (t & 3) << 2;
            const float4 w4 = *(const float4*)(Wt + (size_t)(cm0 + m) * C_ + (k0 + kk));
            Wl[kk + 0][m] = w4.x; Wl[kk + 1][m] = w4.y;
            Wl[kk + 2][m] = w4.z; Wl[kk + 3][m] = w4.w;
        }
        // X tile: Xl[kk][n] = Xb[(k0+kk)*HW + pn0+n]   (coalesced float4)
#pragma unroll
        for (int i = 0; i < 2; ++i) {
            const int flat = (t + (i << 8)) << 2;   // 2048 floats
            const int kk = flat >> 7;
            const int nn = flat & (BN - 1);
            *(float4*)&Xl[kk][nn] = *(const float4*)(Xb + (size_t)(k0 + kk) * HW_ + (pn0 + nn));
        }
        __syncthreads();
#pragma unroll
        for (int kk = 0; kk < BK; ++kk) {
            const float4 wv = *(const float4*)&Wl[kk][ty << 2];
            const float4 x0 = *(const float4*)&Xl[kk][tx << 3];
            const float4 x1 = *(const float4*)&Xl[kk][(tx << 3) + 4];
            const float wr[4] = {wv.x, wv.y, wv.z, wv.w};
            const float xr[8] = {x0.x, x0.y, x0.z, x0.w, x1.x, x1.y, x1.z, x1.w};
#pragma unroll
            for (int i = 0; i < 4; ++i)
#pragma unroll
                for (int j = 0; j < 8; ++j)
                    acc[i][j] = fmaf(wr[i], xr[j], acc[i][j]);
        }
        __syncthreads();
    }

#pragma unroll
    for (int i = 0; i < 4; ++i) {
        const int co = cm0 + (ty << 2) + i;
        const float bb = bias[co];
        const size_t base = (size_t)b * PLANE + (size_t)co * HW_ + pn0 + (tx << 3);
        float o[8];
#pragma unroll
        for (int j = 0; j < 8; ++j) o[j] = acc[i][j] + bb;
        if (RESID) {
            const float4 r0 = *(const float4*)(resid + base);
            const float4 r1 = *(const float4*)(resid + base + 4);
            o[0] += r0.x; o[1] += r0.y; o[2] += r0.z; o[3] += r0.w;
            o[4] += r1.x; o[5] += r1.y; o[6] += r1.z; o[7] += r1.w;
        }
        float4 s0 = {o[0], o[1], o[2], o[3]};
        float4 s1 = {o[4], o[5], o[6], o[7]};
        *(float4*)(Y + base)     = s0;
        *(float4*)(Y + base + 4) = s1;
    }
}

// ---------------------------------------------------------------------------
// scores: per (b,c): S[w][v] = sum_h K[h][w] * Q[h][v]   (128x128x128)
// One block per (b,c). S is written IN-PLACE over Q's slice (all reads of the
// slice complete before the epilogue writes).
// ---------------------------------------------------------------------------
__global__ __launch_bounds__(256)
void scores_k(const float* __restrict__ Kt, float* __restrict__ Q /* also S out */)
{
    constexpr int BK = 32;
    __shared__ float Kl[BK][W_];   // [h][w]
    __shared__ float Ql[BK][W_];   // [h][v]

    const int bc = blockIdx.x;
    const float* Kp = Kt + (size_t)bc * HW_;
    const float* Qp = Q  + (size_t)bc * HW_;
    const int t  = threadIdx.x;
    const int tx = t & 15;   // v block (8)
    const int ty = t >> 4;   // w block (8)

    float acc[8][8];
#pragma unroll
    for (int i = 0; i < 8; ++i)
#pragma unroll
        for (int j = 0; j < 8; ++j) acc[i][j] = 0.f;

    for (int h0 = 0; h0 < H_; h0 += BK) {
#pragma unroll
        for (int i = 0; i < 4; ++i) {
            const int flat = (t + (i << 8)) << 2;    // 4096 floats per array
            const int hh = flat >> 7;
            const int nn = flat & (W_ - 1);
            *(float4*)&Kl[hh][nn] = *(const float4*)(Kp + (size_t)(h0 + hh) * W_ + nn);
            *(float4*)&Ql[hh][nn] = *(const float4*)(Qp + (size_t)(h0 + hh) * W_ + nn);
        }
        __syncthreads();
#pragma unroll 4
        for (int hh = 0; hh < BK; ++hh) {
            const float4 k0 = *(const float4*)&Kl[hh][ty << 3];
            const float4 k1 = *(const float4*)&Kl[hh][(ty << 3) + 4];
            const float4 q0 = *(const float4*)&Ql[hh][tx << 3];
            const float4 q1 = *(const float4*)&Ql[hh][(tx << 3) + 4];
            const float kr[8] = {k0.x, k0.y, k0.z, k0.w, k1.x, k1.y, k1.z, k1.w};
            const float qr[8] = {q0.x, q0.y, q0.z, q0.w, q1.x, q1.y, q1.z, q1.w};
#pragma unroll
            for (int i = 0; i < 8; ++i)
#pragma unroll
                for (int j = 0; j < 8; ++j)
                    acc[i][j] = fmaf(kr[i], qr[j], acc[i][j]);
        }
        __syncthreads();
    }

    float* Sp = Q + (size_t)bc * (size_t)W_ * W_;   // same slice, in place
#pragma unroll
    for (int i = 0; i < 8; ++i) {
        const size_t base = (size_t)((ty << 3) + i) * W_ + (tx << 3);
        float4 s0 = {acc[i][0], acc[i][1], acc[i][2], acc[i][3]};
        float4 s1 = {acc[i][4], acc[i][5], acc[i][6], acc[i][7]};
        *(float4*)(Sp + base)     = s0;
        *(float4*)(Sp + base + 4) = s1;
    }
}

// ---------------------------------------------------------------------------
// softmax over batch axis (8 values, stride = C*W*W elems), in place.
// Each thread: one float4 of (c,w,v) positions x 8 batches.
// ---------------------------------------------------------------------------
__global__ __launch_bounds__(256)
void softmax_b_k(float* __restrict__ S)
{
    const size_t N = (size_t)C_ * W_ * W_;          // 4194304, batch stride
    const size_t idx = ((size_t)blockIdx.x * 256 + threadIdx.x) << 2;
    if (idx >= N) return;

    float4 vals[B_];
#pragma unroll
    for (int b = 0; b < B_; ++b) vals[b] = *(const float4*)(S + (size_t)b * N + idx);

    float4 mx = vals[0];
#pragma unroll
    for (int b = 1; b < B_; ++b) {
        mx.x = fmaxf(mx.x, vals[b].x); mx.y = fmaxf(mx.y, vals[b].y);
        mx.z = fmaxf(mx.z, vals[b].z); mx.w = fmaxf(mx.w, vals[b].w);
    }
    float4 sum = {0.f, 0.f, 0.f, 0.f};
#pragma unroll
    for (int b = 0; b < B_; ++b) {
        vals[b].x = expf(vals[b].x - mx.x); sum.x += vals[b].x;
        vals[b].y = expf(vals[b].y - mx.y); sum.y += vals[b].y;
        vals[b].z = expf(vals[b].z - mx.z); sum.z += vals[b].z;
        vals[b].w = expf(vals[b].w - mx.w); sum.w += vals[b].w;
    }
    const float4 inv = {1.f / sum.x, 1.f / sum.y, 1.f / sum.z, 1.f / sum.w};
#pragma unroll
    for (int b = 0; b < B_; ++b) {
        float4 o = {vals[b].x * inv.x, vals[b].y * inv.y,
                    vals[b].z * inv.z, vals[b].w * inv.w};
        *(float4*)(S + (size_t)b * N + idx) = o;
    }
}

// ---------------------------------------------------------------------------
// AV: per (b,c): O[h][v] = sum_w V[h][w] * A[w][v]   (128x128x128)
// One block per (b,c). O written IN-PLACE over V's slice.
// ---------------------------------------------------------------------------
__global__ __launch_bounds__(256)
void av_k(float* __restrict__ V /* also O out */, const float* __restrict__ A)
{
    constexpr int BK = 32;
    __shared__ float Vl[BK][H_ + 4];   // transposed: Vl[w][h], stride 132 (16B-aligned)
    __shared__ float Al[BK][W_];       // [w][v]

    const int bc = blockIdx.x;
    float* Vp = V + (size_t)bc * HW_;
    const float* Ap = A + (size_t)bc * (size_t)W_ * W_;
    const int t  = threadIdx.x;
    const int tx = t & 15;   // v block
    const int ty = t >> 4;   // h block

    float acc[8][8];
#pragma unroll
    for (int i = 0; i < 8; ++i)
#pragma unroll
        for (int j = 0; j < 8; ++j) acc[i][j] = 0.f;

    for (int w0 = 0; w0 < W_; w0 += BK) {
        // A tile, natural layout (coalesced)
#pragma unroll
        for (int i = 0; i < 4; ++i) {
            const int flat = (t + (i << 8)) << 2;
            const int ww = flat >> 7;
            const int nn = flat & (W_ - 1);
            *(float4*)&Al[ww][nn] = *(const float4*)(Ap + (size_t)(w0 + ww) * W_ + nn);
        }
        // V tile, transposed into LDS: Vl[ww][h] = V[h][w0+ww]
#pragma unroll
        for (int i = 0; i < 4; ++i) {
            const int h  = (t >> 3) + (i << 5);
            const int ww = (t & 7) << 2;
            const float4 v4 = *(const float4*)(Vp + (size_t)h * W_ + (w0 + ww));
            Vl[ww + 0][h] = v4.x; Vl[ww + 1][h] = v4.y;
            Vl[ww + 2][h] = v4.z; Vl[ww + 3][h] = v4.w;
        }
        __syncthreads();
#pragma unroll 4
        for (int ww = 0; ww < BK; ++ww) {
            const float4 v0 = *(const float4*)&Vl[ww][ty << 3];
            const float4 v1 = *(const float4*)&Vl[ww][(ty << 3) + 4];
            const float4 a0 = *(const float4*)&Al[ww][tx << 3];
            const float4 a1 = *(const float4*)&Al[ww][(tx << 3) + 4];
            const float vr[8] = {v0.x, v0.y, v0.z, v0.w, v1.x, v1.y, v1.z, v1.w};
            const float ar[8] = {a0.x, a0.y, a0.z, a0.w, a1.x, a1.y, a1.z, a1.w};
#pragma unroll
            for (int i = 0; i < 8; ++i)
#pragma unroll
                for (int j = 0; j < 8; ++j)
                    acc[i][j] = fmaf(vr[i], ar[j], acc[i][j]);
        }
        __syncthreads();
    }

#pragma unroll
    for (int i = 0; i < 8; ++i) {
        const size_t base = (size_t)((ty << 3) + i) * W_ + (tx << 3);
        float4 s0 = {acc[i][0], acc[i][1], acc[i][2], acc[i][3]};
        float4 s1 = {acc[i][4], acc[i][5], acc[i][6], acc[i][7]};
        *(float4*)(Vp + base)     = s0;
        *(float4*)(Vp + base + 4) = s1;
    }
}

// ---------------------------------------------------------------------------
extern "C" void kernel_launch(void* const* d_in, const int* in_sizes, int n_in,
                              void* d_out, int out_size, void* d_ws, size_t ws_size,
                              hipStream_t stream)
{
    const float* x  = (const float*)d_in[0];
    const float* wk = (const float*)d_in[1];
    const float* bk = (const float*)d_in[2];
    const float* wq = (const float*)d_in[3];
    const float* bq = (const float*)d_in[4];
    const float* wv = (const float*)d_in[5];
    const float* bv = (const float*)d_in[6];
    const float* wo = (const float*)d_in[7];
    const float* bo = (const float*)d_in[8];
    float* out = (float*)d_out;

    // workspace: 3 buffers of B*C*H*W floats (384 MiB total)
    const size_t NBUF = (size_t)B_ * PLANE;   // 33554432
    float* kbuf = (float*)d_ws;               // k            -> free after scores
    float* qbuf = kbuf + NBUF;                // q -> scores -> attn (in place)
    float* vbuf = qbuf + NBUF;                // v -> out2 (in place)

    const dim3 gConv(HW_ / 128, C_ / 64, B_);

    conv1x1_k<false><<<gConv, 256, 0, stream>>>(x, wk, bk, nullptr, kbuf);
    conv1x1_k<false><<<gConv, 256, 0, stream>>>(x, wq, bq, nullptr, qbuf);
    conv1x1_k<false><<<gConv, 256, 0, stream>>>(x, wv, bv, nullptr, vbuf);

    scores_k<<<B_ * C_, 256, 0, stream>>>(kbuf, qbuf);          // qbuf now holds scores
    softmax_b_k<<<4096, 256, 0, stream>>>(qbuf);                // qbuf now holds attn
    av_k<<<B_ * C_, 256, 0, stream>>>(vbuf, qbuf);              // vbuf now holds out2

    conv1x1_k<true><<<gConv, 256, 0, stream>>>(vbuf, wo, bo, x, out);
}

// Round 3
// 1298.844 us; speedup vs baseline: 1.0499x; 1.0499x over previous
//
#include <hip/hip_runtime.h>
#include <math.h>

#define B_ 8
#define C_ 256
#define H_ 128
#define W_ 128
#define HW_ (H_*W_)                 // 16384
#define PLANE ((size_t)C_*HW_)      // 4194304 elems per batch image

// ---------------------------------------------------------------------------
// Fused k/q/v conv1x1: stages one X tile, applies 3 weight tiles.
// Per batch GEMM: M=C(256) x N=HW(16384) x K=C(256), 3 outputs.
// Tile: BM=64, BN=128, BK=16; 256 threads; 3 x (4x8) register tiles.
// Per kk-step: 96 FMA vs 5 ds_read_b128 (was 32 vs 3 per conv).
// ---------------------------------------------------------------------------
__global__ __launch_bounds__(256)
void kqv_conv_k(const float* __restrict__ X,
                const float* __restrict__ Wk, const float* __restrict__ Bk,
                const float* __restrict__ Wq, const float* __restrict__ Bq,
                const float* __restrict__ Wv, const float* __restrict__ Bv,
                float* __restrict__ Ko, float* __restrict__ Qo, float* __restrict__ Vo)
{
    constexpr int BM = 64, BN = 128, BK = 16;
    __shared__ float Wl[3][BK][BM + 4];
    __shared__ float Xl[BK][BN];

    const int b   = blockIdx.z;
    const int cm0 = blockIdx.y * BM;
    const int pn0 = blockIdx.x * BN;
    const int t   = threadIdx.x;
    const int tx  = t & 15;            // n (8 cols)
    const int ty  = t >> 4;            // m (4 rows)
    const float* Xb = X + (size_t)b * PLANE;
    const float* Wp[3] = {Wk, Wq, Wv};

    float acc[3][4][8];
#pragma unroll
    for (int s = 0; s < 3; ++s)
#pragma unroll
        for (int i = 0; i < 4; ++i)
#pragma unroll
            for (int j = 0; j < 8; ++j) acc[s][i][j] = 0.f;

    const int wm  = t >> 2;            // 0..63
    const int wk0 = (t & 3) << 2;      // 0,4,8,12

    for (int k0 = 0; k0 < C_; k0 += BK) {
        // W tiles (transposed into LDS): Wl[s][kk][m] = Ws[cm0+m][k0+kk]
#pragma unroll
        for (int s = 0; s < 3; ++s) {
            const float4 w4 = *(const float4*)(Wp[s] + (size_t)(cm0 + wm) * C_ + (k0 + wk0));
            Wl[s][wk0 + 0][wm] = w4.x; Wl[s][wk0 + 1][wm] = w4.y;
            Wl[s][wk0 + 2][wm] = w4.z; Wl[s][wk0 + 3][wm] = w4.w;
        }
        // X tile: Xl[kk][n], coalesced float4
#pragma unroll
        for (int i = 0; i < 2; ++i) {
            const int flat = (t + (i << 8)) << 2;   // 2048 floats
            const int kk = flat >> 7;
            const int nn = flat & (BN - 1);
            *(float4*)&Xl[kk][nn] = *(const float4*)(Xb + (size_t)(k0 + kk) * HW_ + (pn0 + nn));
        }
        __syncthreads();
#pragma unroll
        for (int kk = 0; kk < BK; ++kk) {
            const float4 x0 = *(const float4*)&Xl[kk][tx << 3];
            const float4 x1 = *(const float4*)&Xl[kk][(tx << 3) + 4];
            const float xr[8] = {x0.x, x0.y, x0.z, x0.w, x1.x, x1.y, x1.z, x1.w};
#pragma unroll
            for (int s = 0; s < 3; ++s) {
                const float4 wv4 = *(const float4*)&Wl[s][kk][ty << 2];
                const float wr[4] = {wv4.x, wv4.y, wv4.z, wv4.w};
#pragma unroll
                for (int i = 0; i < 4; ++i)
#pragma unroll
                    for (int j = 0; j < 8; ++j)
                        acc[s][i][j] = fmaf(wr[i], xr[j], acc[s][i][j]);
            }
        }
        __syncthreads();
    }

    float* Yp[3] = {Ko, Qo, Vo};
    const float* Bp[3] = {Bk, Bq, Bv};
#pragma unroll
    for (int s = 0; s < 3; ++s) {
#pragma unroll
        for (int i = 0; i < 4; ++i) {
            const int co = cm0 + (ty << 2) + i;
            const float bb = Bp[s][co];
            const size_t base = (size_t)b * PLANE + (size_t)co * HW_ + pn0 + (tx << 3);
            float4 s0 = {acc[s][i][0] + bb, acc[s][i][1] + bb, acc[s][i][2] + bb, acc[s][i][3] + bb};
            float4 s1 = {acc[s][i][4] + bb, acc[s][i][5] + bb, acc[s][i][6] + bb, acc[s][i][7] + bb};
            *(float4*)(Yp[s] + base)     = s0;
            *(float4*)(Yp[s] + base + 4) = s1;
        }
    }
}

// ---------------------------------------------------------------------------
// wo conv1x1 + bias + residual: BM=128, BN=128, BK=16; 8x8 register tile.
// ---------------------------------------------------------------------------
__global__ __launch_bounds__(256)
void wo_conv_k(const float* __restrict__ X, const float* __restrict__ Wt,
               const float* __restrict__ bias, const float* __restrict__ resid,
               float* __restrict__ Y)
{
    constexpr int BM = 128, BN = 128, BK = 16;
    __shared__ float Wl[BK][BM + 4];
    __shared__ float Xl[BK][BN];

    const int b   = blockIdx.z;
    const int cm0 = blockIdx.y * BM;
    const int pn0 = blockIdx.x * BN;
    const int t   = threadIdx.x;
    const int tx  = t & 15;            // n (8)
    const int ty  = t >> 4;            // m (8)
    const float* Xb = X + (size_t)b * PLANE;

    float acc[8][8];
#pragma unroll
    for (int i = 0; i < 8; ++i)
#pragma unroll
        for (int j = 0; j < 8; ++j) acc[i][j] = 0.f;

    const int wm  = t >> 1;            // 0..127
    const int wk0 = (t & 1) << 3;      // 0,8

    for (int k0 = 0; k0 < C_; k0 += BK) {
        // W tile transposed: Wl[kk][m] = Wt[cm0+m][k0+kk]  (2 float4 / thread)
        {
            const float4 wa = *(const float4*)(Wt + (size_t)(cm0 + wm) * C_ + (k0 + wk0));
            const float4 wb = *(const float4*)(Wt + (size_t)(cm0 + wm) * C_ + (k0 + wk0 + 4));
            Wl[wk0 + 0][wm] = wa.x; Wl[wk0 + 1][wm] = wa.y;
            Wl[wk0 + 2][wm] = wa.z; Wl[wk0 + 3][wm] = wa.w;
            Wl[wk0 + 4][wm] = wb.x; Wl[wk0 + 5][wm] = wb.y;
            Wl[wk0 + 6][wm] = wb.z; Wl[wk0 + 7][wm] = wb.w;
        }
        // X tile: 2048 floats, 8 per thread
        {
            const int kk = t >> 4;
            const int nn = (t & 15) << 3;
            const float* src = Xb + (size_t)(k0 + kk) * HW_ + (pn0 + nn);
            *(float4*)&Xl[kk][nn]     = *(const float4*)(src);
            *(float4*)&Xl[kk][nn + 4] = *(const float4*)(src + 4);
        }
        __syncthreads();
#pragma unroll
        for (int kk = 0; kk < BK; ++kk) {
            const float4 w0 = *(const float4*)&Wl[kk][ty << 3];
            const float4 w1 = *(const float4*)&Wl[kk][(ty << 3) + 4];
            const float4 x0 = *(const float4*)&Xl[kk][tx << 3];
            const float4 x1 = *(const float4*)&Xl[kk][(tx << 3) + 4];
            const float wr[8] = {w0.x, w0.y, w0.z, w0.w, w1.x, w1.y, w1.z, w1.w};
            const float xr[8] = {x0.x, x0.y, x0.z, x0.w, x1.x, x1.y, x1.z, x1.w};
#pragma unroll
            for (int i = 0; i < 8; ++i)
#pragma unroll
                for (int j = 0; j < 8; ++j)
                    acc[i][j] = fmaf(wr[i], xr[j], acc[i][j]);
        }
        __syncthreads();
    }

#pragma unroll
    for (int i = 0; i < 8; ++i) {
        const int co = cm0 + (ty << 3) + i;
        const float bb = bias[co];
        const size_t base = (size_t)b * PLANE + (size_t)co * HW_ + pn0 + (tx << 3);
        const float4 r0 = *(const float4*)(resid + base);
        const float4 r1 = *(const float4*)(resid + base + 4);
        float4 s0 = {acc[i][0] + bb + r0.x, acc[i][1] + bb + r0.y,
                     acc[i][2] + bb + r0.z, acc[i][3] + bb + r0.w};
        float4 s1 = {acc[i][4] + bb + r1.x, acc[i][5] + bb + r1.y,
                     acc[i][6] + bb + r1.z, acc[i][7] + bb + r1.w};
        *(float4*)(Y + base)     = s0;
        *(float4*)(Y + base + 4) = s1;
    }
}

// ---------------------------------------------------------------------------
// scores: per (b,c): S[w][v] = sum_h K[h][w] * Q[h][v]   (128x128x128)
// One block per (b,c). S written IN-PLACE over Q's slice.
// ---------------------------------------------------------------------------
__global__ __launch_bounds__(256)
void scores_k(const float* __restrict__ Kt, float* __restrict__ Q /* also S out */)
{
    constexpr int BK = 32;
    __shared__ float Kl[BK][W_];   // [h][w]
    __shared__ float Ql[BK][W_];   // [h][v]

    const int bc = blockIdx.x;
    const float* Kp = Kt + (size_t)bc * HW_;
    const float* Qp = Q  + (size_t)bc * HW_;
    const int t  = threadIdx.x;
    const int tx = t & 15;   // v block (8)
    const int ty = t >> 4;   // w block (8)

    float acc[8][8];
#pragma unroll
    for (int i = 0; i < 8; ++i)
#pragma unroll
        for (int j = 0; j < 8; ++j) acc[i][j] = 0.f;

    for (int h0 = 0; h0 < H_; h0 += BK) {
#pragma unroll
        for (int i = 0; i < 4; ++i) {
            const int flat = (t + (i << 8)) << 2;    // 4096 floats per array
            const int hh = flat >> 7;
            const int nn = flat & (W_ - 1);
            *(float4*)&Kl[hh][nn] = *(const float4*)(Kp + (size_t)(h0 + hh) * W_ + nn);
            *(float4*)&Ql[hh][nn] = *(const float4*)(Qp + (size_t)(h0 + hh) * W_ + nn);
        }
        __syncthreads();
#pragma unroll 4
        for (int hh = 0; hh < BK; ++hh) {
            const float4 k0 = *(const float4*)&Kl[hh][ty << 3];
            const float4 k1 = *(const float4*)&Kl[hh][(ty << 3) + 4];
            const float4 q0 = *(const float4*)&Ql[hh][tx << 3];
            const float4 q1 = *(const float4*)&Ql[hh][(tx << 3) + 4];
            const float kr[8] = {k0.x, k0.y, k0.z, k0.w, k1.x, k1.y, k1.z, k1.w};
            const float qr[8] = {q0.x, q0.y, q0.z, q0.w, q1.x, q1.y, q1.z, q1.w};
#pragma unroll
            for (int i = 0; i < 8; ++i)
#pragma unroll
                for (int j = 0; j < 8; ++j)
                    acc[i][j] = fmaf(kr[i], qr[j], acc[i][j]);
        }
        __syncthreads();
    }

    float* Sp = Q + (size_t)bc * (size_t)W_ * W_;   // same slice, in place
#pragma unroll
    for (int i = 0; i < 8; ++i) {
        const size_t base = (size_t)((ty << 3) + i) * W_ + (tx << 3);
        float4 s0 = {acc[i][0], acc[i][1], acc[i][2], acc[i][3]};
        float4 s1 = {acc[i][4], acc[i][5], acc[i][6], acc[i][7]};
        *(float4*)(Sp + base)     = s0;
        *(float4*)(Sp + base + 4) = s1;
    }
}

// ---------------------------------------------------------------------------
// softmax over batch axis (8 values, stride = C*W*W elems), in place.
// ---------------------------------------------------------------------------
__global__ __launch_bounds__(256)
void softmax_b_k(float* __restrict__ S)
{
    const size_t N = (size_t)C_ * W_ * W_;          // 4194304, batch stride
    const size_t idx = ((size_t)blockIdx.x * 256 + threadIdx.x) << 2;
    if (idx >= N) return;

    float4 vals[B_];
#pragma unroll
    for (int b = 0; b < B_; ++b) vals[b] = *(const float4*)(S + (size_t)b * N + idx);

    float4 mx = vals[0];
#pragma unroll
    for (int b = 1; b < B_; ++b) {
        mx.x = fmaxf(mx.x, vals[b].x); mx.y = fmaxf(mx.y, vals[b].y);
        mx.z = fmaxf(mx.z, vals[b].z); mx.w = fmaxf(mx.w, vals[b].w);
    }
    float4 sum = {0.f, 0.f, 0.f, 0.f};
#pragma unroll
    for (int b = 0; b < B_; ++b) {
        vals[b].x = expf(vals[b].x - mx.x); sum.x += vals[b].x;
        vals[b].y = expf(vals[b].y - mx.y); sum.y += vals[b].y;
        vals[b].z = expf(vals[b].z - mx.z); sum.z += vals[b].z;
        vals[b].w = expf(vals[b].w - mx.w); sum.w += vals[b].w;
    }
    const float4 inv = {1.f / sum.x, 1.f / sum.y, 1.f / sum.z, 1.f / sum.w};
#pragma unroll
    for (int b = 0; b < B_; ++b) {
        float4 o = {vals[b].x * inv.x, vals[b].y * inv.y,
                    vals[b].z * inv.z, vals[b].w * inv.w};
        *(float4*)(S + (size_t)b * N + idx) = o;
    }
}

// ---------------------------------------------------------------------------
// AV: per (b,c): O[h][v] = sum_w V[h][w] * A[w][v]   (128x128x128)
// One block per (b,c). O written IN-PLACE over V's slice.
// ---------------------------------------------------------------------------
__global__ __launch_bounds__(256)
void av_k(float* __restrict__ V /* also O out */, const float* __restrict__ A)
{
    constexpr int BK = 32;
    __shared__ float Vl[BK][H_ + 4];   // transposed: Vl[w][h]
    __shared__ float Al[BK][W_];       // [w][v]

    const int bc = blockIdx.x;
    float* Vp = V + (size_t)bc * HW_;
    const float* Ap = A + (size_t)bc * (size_t)W_ * W_;
    const int t  = threadIdx.x;
    const int tx = t & 15;   // v block
    const int ty = t >> 4;   // h block

    float acc[8][8];
#pragma unroll
    for (int i = 0; i < 8; ++i)
#pragma unroll
        for (int j = 0; j < 8; ++j) acc[i][j] = 0.f;

    for (int w0 = 0; w0 < W_; w0 += BK) {
#pragma unroll
        for (int i = 0; i < 4; ++i) {
            const int flat = (t + (i << 8)) << 2;
            const int ww = flat >> 7;
            const int nn = flat & (W_ - 1);
            *(float4*)&Al[ww][nn] = *(const float4*)(Ap + (size_t)(w0 + ww) * W_ + nn);
        }
#pragma unroll
        for (int i = 0; i < 4; ++i) {
            const int h  = (t >> 3) + (i << 5);
            const int ww = (t & 7) << 2;
            const float4 v4 = *(const float4*)(Vp + (size_t)h * W_ + (w0 + ww));
            Vl[ww + 0][h] = v4.x; Vl[ww + 1][h] = v4.y;
            Vl[ww + 2][h] = v4.z; Vl[ww + 3][h] = v4.w;
        }
        __syncthreads();
#pragma unroll 4
        for (int ww = 0; ww < BK; ++ww) {
            const float4 v0 = *(const float4*)&Vl[ww][ty << 3];
            const float4 v1 = *(const float4*)&Vl[ww][(ty << 3) + 4];
            const float4 a0 = *(const float4*)&Al[ww][tx << 3];
            const float4 a1 = *(const float4*)&Al[ww][(tx << 3) + 4];
            const float vr[8] = {v0.x, v0.y, v0.z, v0.w, v1.x, v1.y, v1.z, v1.w};
            const float ar[8] = {a0.x, a0.y, a0.z, a0.w, a1.x, a1.y, a1.z, a1.w};
#pragma unroll
            for (int i = 0; i < 8; ++i)
#pragma unroll
                for (int j = 0; j < 8; ++j)
                    acc[i][j] = fmaf(vr[i], ar[j], acc[i][j]);
        }
        __syncthreads();
    }

#pragma unroll
    for (int i = 0; i < 8; ++i) {
        const size_t base = (size_t)((ty << 3) + i) * W_ + (tx << 3);
        float4 s0 = {acc[i][0], acc[i][1], acc[i][2], acc[i][3]};
        float4 s1 = {acc[i][4], acc[i][5], acc[i][6], acc[i][7]};
        *(float4*)(Vp + base)     = s0;
        *(float4*)(Vp + base + 4) = s1;
    }
}

// ---------------------------------------------------------------------------
extern "C" void kernel_launch(void* const* d_in, const int* in_sizes, int n_in,
                              void* d_out, int out_size, void* d_ws, size_t ws_size,
                              hipStream_t stream)
{
    const float* x  = (const float*)d_in[0];
    const float* wk = (const float*)d_in[1];
    const float* bk = (const float*)d_in[2];
    const float* wq = (const float*)d_in[3];
    const float* bq = (const float*)d_in[4];
    const float* wv = (const float*)d_in[5];
    const float* bv = (const float*)d_in[6];
    const float* wo = (const float*)d_in[7];
    const float* bo = (const float*)d_in[8];
    float* out = (float*)d_out;

    const size_t NBUF = (size_t)B_ * PLANE;   // 33554432 elems
    float* kbuf = (float*)d_ws;
    float* qbuf = kbuf + NBUF;                // q -> scores -> attn (in place)
    float* vbuf = qbuf + NBUF;                // v -> out2 (in place)

    const dim3 gKQV(HW_ / 128, C_ / 64, B_);
    kqv_conv_k<<<gKQV, 256, 0, stream>>>(x, wk, bk, wq, bq, wv, bv, kbuf, qbuf, vbuf);

    scores_k<<<B_ * C_, 256, 0, stream>>>(kbuf, qbuf);          // qbuf := scores
    softmax_b_k<<<4096, 256, 0, stream>>>(qbuf);                // qbuf := attn
    av_k<<<B_ * C_, 256, 0, stream>>>(vbuf, qbuf);              // vbuf := out2

    const dim3 gWO(HW_ / 128, C_ / 128, B_);
    wo_conv_k<<<gWO, 256, 0, stream>>>(vbuf, wo, bo, x, out);
}

// Round 4
// 911.971 us; speedup vs baseline: 1.4953x; 1.4242x over previous
//
#include <hip/hip_runtime.h>
#include <math.h>

#define B_ 8
#define C_ 256
#define H_ 128
#define W_ 128
#define HW_ (H_*W_)                 // 16384
#define PLANE ((size_t)C_*HW_)      // 4194304 elems per batch image

typedef __attribute__((ext_vector_type(8))) short short8;   // 8 bf16 (4 VGPR)
typedef __attribute__((ext_vector_type(4))) float f32x4;    // MFMA acc

// f32 -> bf16 (round-to-nearest-even), bit pattern in ushort
static __device__ __forceinline__ unsigned short f2bf(float f) {
    unsigned u = __float_as_uint(f);
    u += 0x7FFF + ((u >> 16) & 1);
    return (unsigned short)(u >> 16);
}
static __device__ __forceinline__ float bf2f(unsigned short h) {
    return __uint_as_float(((unsigned)h) << 16);
}

// Swizzled byte offset inside a [rows][32]-bf16 LDS plane (row stride 64B).
// XOR of bits 4..6 by (row&7): bijective; spreads 16-consecutive-row b128
// frag reads across all 8 bank-quads (2 lanes/bank = free).
#define SWZ(row, kbyte) ((((row) << 6) | (kbyte)) ^ (((row) & 7) << 4))

// ---------------------------------------------------------------------------
// conv1x1 via MFMA bf16x3 split (fp32-accurate):
//   Y_s[b][co][p] = sum_ci W_s[co][ci] * X[b][ci][p] + bias_s[co] (+resid)
// A = W (m=co, k=ci), B = X^T-in-LDS (n=p, k=ci), D: col=n(p), row=m(co).
// NS weight sets share one staged X tile. Block: MPS*NS co-rows x 128 p,
// BK=32, 4 waves (each wave owns 32 p), 256 threads.
// ---------------------------------------------------------------------------
template<int NS, int MPS, bool RESID>
__global__ __launch_bounds__(256)
void conv_mfma(const float* __restrict__ X,
               const float* __restrict__ W0, const float* __restrict__ W1,
               const float* __restrict__ W2,
               const float* __restrict__ Bi0, const float* __restrict__ Bi1,
               const float* __restrict__ Bi2,
               const float* __restrict__ resid,
               float* __restrict__ Y0, float* __restrict__ Y1,
               float* __restrict__ Y2)
{
    constexpr int NROWS = NS * MPS;     // A-tile rows (co across all s)
    constexpr int MREP  = MPS / 16;
    constexpr int BN = 128, BK = 32;

    __shared__ unsigned short AhT[NROWS * BK], AlT[NROWS * BK];
    __shared__ unsigned short BhT[BN * BK],   BlT[BN * BK];
    __shared__ float biasLds[NROWS];

    const int b    = blockIdx.z;
    const int co0  = blockIdx.y * MPS;   // per-s co base
    const int p0   = blockIdx.x * BN;
    const int t    = threadIdx.x;
    const int lane = t & 63;
    const int wv   = t >> 6;

    const float* Wp[3] = {W0, W1, W2};
    const float* Bp[3] = {Bi0, Bi1, Bi2};
    float*       Yp[3] = {Y0, Y1, Y2};
    const float* Xb = X + (size_t)b * PLANE;

    if (t < NROWS) {
        const int s = t / MPS, r = t % MPS;
        biasLds[t] = Bp[s][co0 + r];
    }

    f32x4 acc[NS][MREP][2];
#pragma unroll
    for (int s = 0; s < NS; ++s)
#pragma unroll
        for (int mr = 0; mr < MREP; ++mr)
#pragma unroll
            for (int nr = 0; nr < 2; ++nr)
                acc[s][mr][nr] = (f32x4){0.f, 0.f, 0.f, 0.f};

    const int kb = (lane >> 4) << 4;     // frag k-byte offset: 16*(l>>4)

    for (int k0 = 0; k0 < C_; k0 += BK) {
        // ---- stage A (weights): rows k-contiguous, b64 writes, swizzled ----
#pragma unroll
        for (int i = 0; i < NROWS / 32; ++i) {
            const int idx = t + (i << 8);
            const int row = idx >> 3;            // 0..NROWS-1
            const int q4  = (idx & 7) << 2;      // k elem offset 0,4,..,28
            const int s   = row / MPS;
            const int cl  = row % MPS;
            const float4 w4 = *(const float4*)(Wp[s] + (size_t)(co0 + cl) * C_ + (k0 + q4));
            const unsigned short h0 = f2bf(w4.x), h1 = f2bf(w4.y),
                                 h2 = f2bf(w4.z), h3 = f2bf(w4.w);
            const ushort4 hv = {h0, h1, h2, h3};
            const ushort4 lv = {f2bf(w4.x - bf2f(h0)), f2bf(w4.y - bf2f(h1)),
                                f2bf(w4.z - bf2f(h2)), f2bf(w4.w - bf2f(h3))};
            *(ushort4*)((char*)AhT + SWZ(row, q4 << 1)) = hv;
            *(ushort4*)((char*)AlT + SWZ(row, q4 << 1)) = lv;
        }
        // ---- stage B (X tile), transposed into [p][ci] bf16 planes ----
#pragma unroll
        for (int i = 0; i < 4; ++i) {
            const int ci = (i << 3) + (t & 7);   // 0..31
            const int p4 = (t >> 3) << 2;        // 0..124
            const float4 x4 = *(const float4*)(Xb + (size_t)(k0 + ci) * HW_ + (p0 + p4));
            const float xe[4] = {x4.x, x4.y, x4.z, x4.w};
#pragma unroll
            for (int e = 0; e < 4; ++e) {
                const unsigned short hh = f2bf(xe[e]);
                const unsigned short ll = f2bf(xe[e] - bf2f(hh));
                *(unsigned short*)((char*)BhT + SWZ(p4 + e, ci << 1)) = hh;
                *(unsigned short*)((char*)BlT + SWZ(p4 + e, ci << 1)) = ll;
            }
        }
        __syncthreads();

        // ---- B fragments (shared across s) ----
        short8 bfh[2], bfl[2];
        const int prow_base = (wv << 5) + (lane & 15);
#pragma unroll
        for (int nr = 0; nr < 2; ++nr) {
            const int prow = prow_base + (nr << 4);
            bfh[nr] = *(short8*)((char*)BhT + SWZ(prow, kb));
            bfl[nr] = *(short8*)((char*)BlT + SWZ(prow, kb));
        }
        // ---- A fragments + MFMA (3-term split) ----
#pragma unroll
        for (int s = 0; s < NS; ++s) {
#pragma unroll
            for (int mr = 0; mr < MREP; ++mr) {
                const int arow = s * MPS + (mr << 4) + (lane & 15);
                const short8 afh = *(short8*)((char*)AhT + SWZ(arow, kb));
                const short8 afl = *(short8*)((char*)AlT + SWZ(arow, kb));
#pragma unroll
                for (int nr = 0; nr < 2; ++nr) {
                    acc[s][mr][nr] = __builtin_amdgcn_mfma_f32_16x16x32_bf16(
                        afh, bfh[nr], acc[s][mr][nr], 0, 0, 0);
                    acc[s][mr][nr] = __builtin_amdgcn_mfma_f32_16x16x32_bf16(
                        afh, bfl[nr], acc[s][mr][nr], 0, 0, 0);
                    acc[s][mr][nr] = __builtin_amdgcn_mfma_f32_16x16x32_bf16(
                        afl, bfh[nr], acc[s][mr][nr], 0, 0, 0);
                }
            }
        }
        __syncthreads();
    }

    // ---- epilogue: D col = n (p, lane&15), rows m = 4*(l>>4)+reg ----
    const int r4   = (lane >> 4) << 2;
    const int pcol = p0 + (wv << 5) + (lane & 15);
#pragma unroll
    for (int s = 0; s < NS; ++s) {
        float* Y = Yp[s];
#pragma unroll
        for (int mr = 0; mr < MREP; ++mr) {
#pragma unroll
            for (int nr = 0; nr < 2; ++nr) {
                const f32x4 a = acc[s][mr][nr];
#pragma unroll
                for (int r = 0; r < 4; ++r) {
                    const int cl = (mr << 4) + r4 + r;
                    const int co = co0 + cl;
                    const size_t addr = (size_t)b * PLANE + (size_t)co * HW_
                                      + (size_t)(pcol + (nr << 4));
                    float val = a[r] + biasLds[s * MPS + cl];
                    if (RESID) val += resid[addr];
                    Y[addr] = val;
                }
            }
        }
    }
}

// ---------------------------------------------------------------------------
// scores: per (b,c): S[w][v] = sum_h K[h][w] * Q[h][v]   (128x128x128)
// One block per (b,c). S written IN-PLACE over Q's slice.  (unchanged)
// ---------------------------------------------------------------------------
__global__ __launch_bounds__(256)
void scores_k(const float* __restrict__ Kt, float* __restrict__ Q /* also S out */)
{
    constexpr int BK = 32;
    __shared__ float Kl[BK][W_];
    __shared__ float Ql[BK][W_];

    const int bc = blockIdx.x;
    const float* Kp = Kt + (size_t)bc * HW_;
    const float* Qp = Q  + (size_t)bc * HW_;
    const int t  = threadIdx.x;
    const int tx = t & 15;
    const int ty = t >> 4;

    float acc[8][8];
#pragma unroll
    for (int i = 0; i < 8; ++i)
#pragma unroll
        for (int j = 0; j < 8; ++j) acc[i][j] = 0.f;

    for (int h0 = 0; h0 < H_; h0 += BK) {
#pragma unroll
        for (int i = 0; i < 4; ++i) {
            const int flat = (t + (i << 8)) << 2;
            const int hh = flat >> 7;
            const int nn = flat & (W_ - 1);
            *(float4*)&Kl[hh][nn] = *(const float4*)(Kp + (size_t)(h0 + hh) * W_ + nn);
            *(float4*)&Ql[hh][nn] = *(const float4*)(Qp + (size_t)(h0 + hh) * W_ + nn);
        }
        __syncthreads();
#pragma unroll 4
        for (int hh = 0; hh < BK; ++hh) {
            const float4 k0 = *(const float4*)&Kl[hh][ty << 3];
            const float4 k1 = *(const float4*)&Kl[hh][(ty << 3) + 4];
            const float4 q0 = *(const float4*)&Ql[hh][tx << 3];
            const float4 q1 = *(const float4*)&Ql[hh][(tx << 3) + 4];
            const float kr[8] = {k0.x, k0.y, k0.z, k0.w, k1.x, k1.y, k1.z, k1.w};
            const float qr[8] = {q0.x, q0.y, q0.z, q0.w, q1.x, q1.y, q1.z, q1.w};
#pragma unroll
            for (int i = 0; i < 8; ++i)
#pragma unroll
                for (int j = 0; j < 8; ++j)
                    acc[i][j] = fmaf(kr[i], qr[j], acc[i][j]);
        }
        __syncthreads();
    }

    float* Sp = Q + (size_t)bc * (size_t)W_ * W_;
#pragma unroll
    for (int i = 0; i < 8; ++i) {
        const size_t base = (size_t)((ty << 3) + i) * W_ + (tx << 3);
        float4 s0 = {acc[i][0], acc[i][1], acc[i][2], acc[i][3]};
        float4 s1 = {acc[i][4], acc[i][5], acc[i][6], acc[i][7]};
        *(float4*)(Sp + base)     = s0;
        *(float4*)(Sp + base + 4) = s1;
    }
}

// ---------------------------------------------------------------------------
// softmax over batch axis (8 values, stride = C*W*W elems), in place. (unchanged)
// ---------------------------------------------------------------------------
__global__ __launch_bounds__(256)
void softmax_b_k(float* __restrict__ S)
{
    const size_t N = (size_t)C_ * W_ * W_;
    const size_t idx = ((size_t)blockIdx.x * 256 + threadIdx.x) << 2;
    if (idx >= N) return;

    float4 vals[B_];
#pragma unroll
    for (int b = 0; b < B_; ++b) vals[b] = *(const float4*)(S + (size_t)b * N + idx);

    float4 mx = vals[0];
#pragma unroll
    for (int b = 1; b < B_; ++b) {
        mx.x = fmaxf(mx.x, vals[b].x); mx.y = fmaxf(mx.y, vals[b].y);
        mx.z = fmaxf(mx.z, vals[b].z); mx.w = fmaxf(mx.w, vals[b].w);
    }
    float4 sum = {0.f, 0.f, 0.f, 0.f};
#pragma unroll
    for (int b = 0; b < B_; ++b) {
        vals[b].x = expf(vals[b].x - mx.x); sum.x += vals[b].x;
        vals[b].y = expf(vals[b].y - mx.y); sum.y += vals[b].y;
        vals[b].z = expf(vals[b].z - mx.z); sum.z += vals[b].z;
        vals[b].w = expf(vals[b].w - mx.w); sum.w += vals[b].w;
    }
    const float4 inv = {1.f / sum.x, 1.f / sum.y, 1.f / sum.z, 1.f / sum.w};
#pragma unroll
    for (int b = 0; b < B_; ++b) {
        float4 o = {vals[b].x * inv.x, vals[b].y * inv.y,
                    vals[b].z * inv.z, vals[b].w * inv.w};
        *(float4*)(S + (size_t)b * N + idx) = o;
    }
}

// ---------------------------------------------------------------------------
// AV: per (b,c): O[h][v] = sum_w V[h][w] * A[w][v]. In-place over V. (unchanged)
// ---------------------------------------------------------------------------
__global__ __launch_bounds__(256)
void av_k(float* __restrict__ V /* also O out */, const float* __restrict__ A)
{
    constexpr int BK = 32;
    __shared__ float Vl[BK][H_ + 4];
    __shared__ float Al[BK][W_];

    const int bc = blockIdx.x;
    float* Vp = V + (size_t)bc * HW_;
    const float* Ap = A + (size_t)bc * (size_t)W_ * W_;
    const int t  = threadIdx.x;
    const int tx = t & 15;
    const int ty = t >> 4;

    float acc[8][8];
#pragma unroll
    for (int i = 0; i < 8; ++i)
#pragma unroll
        for (int j = 0; j < 8; ++j) acc[i][j] = 0.f;

    for (int w0 = 0; w0 < W_; w0 += BK) {
#pragma unroll
        for (int i = 0; i < 4; ++i) {
            const int flat = (t + (i << 8)) << 2;
            const int ww = flat >> 7;
            const int nn = flat & (W_ - 1);
            *(float4*)&Al[ww][nn] = *(const float4*)(Ap + (size_t)(w0 + ww) * W_ + nn);
        }
#pragma unroll
        for (int i = 0; i < 4; ++i) {
            const int h  = (t >> 3) + (i << 5);
            const int ww = (t & 7) << 2;
            const float4 v4 = *(const float4*)(Vp + (size_t)h * W_ + (w0 + ww));
            Vl[ww + 0][h] = v4.x; Vl[ww + 1][h] = v4.y;
            Vl[ww + 2][h] = v4.z; Vl[ww + 3][h] = v4.w;
        }
        __syncthreads();
#pragma unroll 4
        for (int ww = 0; ww < BK; ++ww) {
            const float4 v0 = *(const float4*)&Vl[ww][ty << 3];
            const float4 v1 = *(const float4*)&Vl[ww][(ty << 3) + 4];
            const float4 a0 = *(const float4*)&Al[ww][tx << 3];
            const float4 a1 = *(const float4*)&Al[ww][(tx << 3) + 4];
            const float vr[8] = {v0.x, v0.y, v0.z, v0.w, v1.x, v1.y, v1.z, v1.w};
            const float ar[8] = {a0.x, a0.y, a0.z, a0.w, a1.x, a1.y, a1.z, a1.w};
#pragma unroll
            for (int i = 0; i < 8; ++i)
#pragma unroll
                for (int j = 0; j < 8; ++j)
                    acc[i][j] = fmaf(vr[i], ar[j], acc[i][j]);
        }
        __syncthreads();
    }

#pragma unroll
    for (int i = 0; i < 8; ++i) {
        const size_t base = (size_t)((ty << 3) + i) * W_ + (tx << 3);
        float4 s0 = {acc[i][0], acc[i][1], acc[i][2], acc[i][3]};
        float4 s1 = {acc[i][4], acc[i][5], acc[i][6], acc[i][7]};
        *(float4*)(Vp + base)     = s0;
        *(float4*)(Vp + base + 4) = s1;
    }
}

// ---------------------------------------------------------------------------
extern "C" void kernel_launch(void* const* d_in, const int* in_sizes, int n_in,
                              void* d_out, int out_size, void* d_ws, size_t ws_size,
                              hipStream_t stream)
{
    const float* x  = (const float*)d_in[0];
    const float* wk = (const float*)d_in[1];
    const float* bk = (const float*)d_in[2];
    const float* wq = (const float*)d_in[3];
    const float* bq = (const float*)d_in[4];
    const float* wv = (const float*)d_in[5];
    const float* bv = (const float*)d_in[6];
    const float* wo = (const float*)d_in[7];
    const float* bo = (const float*)d_in[8];
    float* out = (float*)d_out;

    const size_t NBUF = (size_t)B_ * PLANE;   // 33554432 elems (384 MiB total ws)
    float* kbuf = (float*)d_ws;
    float* qbuf = kbuf + NBUF;                // q -> scores -> attn (in place)
    float* vbuf = qbuf + NBUF;                // v -> out2 (in place)

    // fused k/q/v conv via MFMA bf16x3
    const dim3 gKQV(HW_ / 128, C_ / 32, B_);
    conv_mfma<3, 32, false><<<gKQV, 256, 0, stream>>>(
        x, wk, wq, wv, bk, bq, bv, nullptr, kbuf, qbuf, vbuf);

    scores_k<<<B_ * C_, 256, 0, stream>>>(kbuf, qbuf);   // qbuf := scores
    softmax_b_k<<<4096, 256, 0, stream>>>(qbuf);         // qbuf := attn
    av_k<<<B_ * C_, 256, 0, stream>>>(vbuf, qbuf);       // vbuf := out2

    // wo conv + bias + residual via MFMA bf16x3
    const dim3 gWO(HW_ / 128, C_ / 64, B_);
    conv_mfma<1, 64, true><<<gWO, 256, 0, stream>>>(
        vbuf, wo, nullptr, nullptr, bo, nullptr, nullptr, x, out, nullptr, nullptr);
}

// Round 5
// 870.408 us; speedup vs baseline: 1.5667x; 1.0478x over previous
//
#include <hip/hip_runtime.h>
#include <math.h>

#define B_ 8
#define C_ 256
#define H_ 128
#define W_ 128
#define HW_ (H_*W_)                 // 16384
#define PLANE ((size_t)C_*HW_)      // 4194304 elems per batch image

typedef __attribute__((ext_vector_type(8))) short short8;   // 8 bf16 (4 VGPR)
typedef __attribute__((ext_vector_type(4))) float f32x4;    // MFMA acc

// f32 -> bf16 (round-to-nearest-even), bit pattern in ushort
static __device__ __forceinline__ unsigned short f2bf(float f) {
    unsigned u = __float_as_uint(f);
    u += 0x7FFF + ((u >> 16) & 1);
    return (unsigned short)(u >> 16);
}
static __device__ __forceinline__ float bf2f(unsigned short h) {
    return __uint_as_float(((unsigned)h) << 16);
}

// Swizzled byte offset inside a [rows][32]-bf16 LDS plane (row stride 64B).
// XOR bits 4..6 by (row&7): bijective, preserves bits 0..3 (so 4/8/16B-aligned
// chunks stay aligned); spreads 16-consecutive-row b128 frag reads across
// bank quads (2 lanes/bank = free).
#define SWZ(row, kbyte) ((((row) << 6) | (kbyte)) ^ (((row) & 7) << 4))

// ---------------------------------------------------------------------------
// conv1x1 via MFMA bf16x3 split (fp32-accurate). UNCHANGED from round 4.
// ---------------------------------------------------------------------------
template<int NS, int MPS, bool RESID>
__global__ __launch_bounds__(256)
void conv_mfma(const float* __restrict__ X,
               const float* __restrict__ W0, const float* __restrict__ W1,
               const float* __restrict__ W2,
               const float* __restrict__ Bi0, const float* __restrict__ Bi1,
               const float* __restrict__ Bi2,
               const float* __restrict__ resid,
               float* __restrict__ Y0, float* __restrict__ Y1,
               float* __restrict__ Y2)
{
    constexpr int NROWS = NS * MPS;
    constexpr int MREP  = MPS / 16;
    constexpr int BN = 128, BK = 32;

    __shared__ unsigned short AhT[NROWS * BK], AlT[NROWS * BK];
    __shared__ unsigned short BhT[BN * BK],   BlT[BN * BK];
    __shared__ float biasLds[NROWS];

    const int b    = blockIdx.z;
    const int co0  = blockIdx.y * MPS;
    const int p0   = blockIdx.x * BN;
    const int t    = threadIdx.x;
    const int lane = t & 63;
    const int wv   = t >> 6;

    const float* Wp[3] = {W0, W1, W2};
    const float* Bp[3] = {Bi0, Bi1, Bi2};
    float*       Yp[3] = {Y0, Y1, Y2};
    const float* Xb = X + (size_t)b * PLANE;

    if (t < NROWS) {
        const int s = t / MPS, r = t % MPS;
        biasLds[t] = Bp[s][co0 + r];
    }

    f32x4 acc[NS][MREP][2];
#pragma unroll
    for (int s = 0; s < NS; ++s)
#pragma unroll
        for (int mr = 0; mr < MREP; ++mr)
#pragma unroll
            for (int nr = 0; nr < 2; ++nr)
                acc[s][mr][nr] = (f32x4){0.f, 0.f, 0.f, 0.f};

    const int kb = (lane >> 4) << 4;

    for (int k0 = 0; k0 < C_; k0 += BK) {
#pragma unroll
        for (int i = 0; i < NROWS / 32; ++i) {
            const int idx = t + (i << 8);
            const int row = idx >> 3;
            const int q4  = (idx & 7) << 2;
            const int s   = row / MPS;
            const int cl  = row % MPS;
            const float4 w4 = *(const float4*)(Wp[s] + (size_t)(co0 + cl) * C_ + (k0 + q4));
            const unsigned short h0 = f2bf(w4.x), h1 = f2bf(w4.y),
                                 h2 = f2bf(w4.z), h3 = f2bf(w4.w);
            const ushort4 hv = {h0, h1, h2, h3};
            const ushort4 lv = {f2bf(w4.x - bf2f(h0)), f2bf(w4.y - bf2f(h1)),
                                f2bf(w4.z - bf2f(h2)), f2bf(w4.w - bf2f(h3))};
            *(ushort4*)((char*)AhT + SWZ(row, q4 << 1)) = hv;
            *(ushort4*)((char*)AlT + SWZ(row, q4 << 1)) = lv;
        }
#pragma unroll
        for (int i = 0; i < 4; ++i) {
            const int ci = (i << 3) + (t & 7);
            const int p4 = (t >> 3) << 2;
            const float4 x4 = *(const float4*)(Xb + (size_t)(k0 + ci) * HW_ + (p0 + p4));
            const float xe[4] = {x4.x, x4.y, x4.z, x4.w};
#pragma unroll
            for (int e = 0; e < 4; ++e) {
                const unsigned short hh = f2bf(xe[e]);
                const unsigned short ll = f2bf(xe[e] - bf2f(hh));
                *(unsigned short*)((char*)BhT + SWZ(p4 + e, ci << 1)) = hh;
                *(unsigned short*)((char*)BlT + SWZ(p4 + e, ci << 1)) = ll;
            }
        }
        __syncthreads();

        short8 bfh[2], bfl[2];
        const int prow_base = (wv << 5) + (lane & 15);
#pragma unroll
        for (int nr = 0; nr < 2; ++nr) {
            const int prow = prow_base + (nr << 4);
            bfh[nr] = *(short8*)((char*)BhT + SWZ(prow, kb));
            bfl[nr] = *(short8*)((char*)BlT + SWZ(prow, kb));
        }
#pragma unroll
        for (int s = 0; s < NS; ++s) {
#pragma unroll
            for (int mr = 0; mr < MREP; ++mr) {
                const int arow = s * MPS + (mr << 4) + (lane & 15);
                const short8 afh = *(short8*)((char*)AhT + SWZ(arow, kb));
                const short8 afl = *(short8*)((char*)AlT + SWZ(arow, kb));
#pragma unroll
                for (int nr = 0; nr < 2; ++nr) {
                    acc[s][mr][nr] = __builtin_amdgcn_mfma_f32_16x16x32_bf16(
                        afh, bfh[nr], acc[s][mr][nr], 0, 0, 0);
                    acc[s][mr][nr] = __builtin_amdgcn_mfma_f32_16x16x32_bf16(
                        afh, bfl[nr], acc[s][mr][nr], 0, 0, 0);
                    acc[s][mr][nr] = __builtin_amdgcn_mfma_f32_16x16x32_bf16(
                        afl, bfh[nr], acc[s][mr][nr], 0, 0, 0);
                }
            }
        }
        __syncthreads();
    }

    const int r4   = (lane >> 4) << 2;
    const int pcol = p0 + (wv << 5) + (lane & 15);
#pragma unroll
    for (int s = 0; s < NS; ++s) {
        float* Y = Yp[s];
#pragma unroll
        for (int mr = 0; mr < MREP; ++mr) {
#pragma unroll
            for (int nr = 0; nr < 2; ++nr) {
                const f32x4 a = acc[s][mr][nr];
#pragma unroll
                for (int r = 0; r < 4; ++r) {
                    const int cl = (mr << 4) + r4 + r;
                    const int co = co0 + cl;
                    const size_t addr = (size_t)b * PLANE + (size_t)co * HW_
                                      + (size_t)(pcol + (nr << 4));
                    float val = a[r] + biasLds[s * MPS + cl];
                    if (RESID) val += resid[addr];
                    Y[addr] = val;
                }
            }
        }
    }
}

// ---------------------------------------------------------------------------
// scores via MFMA bf16x3: per (b,c): ST[v][w] = sum_h Q[h][v]*K[h][w]
// (= reference scores[w][v], stored transposed). A=Q^T (m=v,k=h),
// B=K^T (n=w,k=h); both transposed+split into swizzled LDS planes.
// 4 waves; wave owns 32 v-rows x 128 w. ST written IN-PLACE over Q slice.
// ---------------------------------------------------------------------------
__global__ __launch_bounds__(256)
void scores_mfma(const float* __restrict__ Kt, float* __restrict__ Q)
{
    __shared__ unsigned short QTh[128 * 32], QTl[128 * 32];
    __shared__ unsigned short KTh[128 * 32], KTl[128 * 32];

    const int bc = blockIdx.x;
    const float* Kp = Kt + (size_t)bc * HW_;
    const float* Qp = Q  + (size_t)bc * HW_;
    const int t = threadIdx.x, lane = t & 63, wv = t >> 6;

    const int hhp = t & 15;            // k-pair index (h = 2*hhp, 2*hhp+1)
    const int vc  = (t >> 4) << 3;     // 8-elem column chunk (0..120)
    const int kb  = (lane >> 4) << 4;  // frag k-byte offset

    f32x4 acc[2][8];
#pragma unroll
    for (int mr = 0; mr < 2; ++mr)
#pragma unroll
        for (int nr = 0; nr < 8; ++nr)
            acc[mr][nr] = (f32x4){0.f, 0.f, 0.f, 0.f};

    for (int h0 = 0; h0 < H_; h0 += 32) {
        float qv[2][8], kv[2][8];
#pragma unroll
        for (int j = 0; j < 2; ++j) {
            const int hh = h0 + (hhp << 1) + j;
            const float4 q0 = *(const float4*)(Qp + (size_t)hh * W_ + vc);
            const float4 q1 = *(const float4*)(Qp + (size_t)hh * W_ + vc + 4);
            const float4 k0 = *(const float4*)(Kp + (size_t)hh * W_ + vc);
            const float4 k1 = *(const float4*)(Kp + (size_t)hh * W_ + vc + 4);
            qv[j][0]=q0.x; qv[j][1]=q0.y; qv[j][2]=q0.z; qv[j][3]=q0.w;
            qv[j][4]=q1.x; qv[j][5]=q1.y; qv[j][6]=q1.z; qv[j][7]=q1.w;
            kv[j][0]=k0.x; kv[j][1]=k0.y; kv[j][2]=k0.z; kv[j][3]=k0.w;
            kv[j][4]=k1.x; kv[j][5]=k1.y; kv[j][6]=k1.z; kv[j][7]=k1.w;
        }
#pragma unroll
        for (int e = 0; e < 8; ++e) {
            const int v = vc + e;
            const int off = SWZ(v, hhp << 2);
            const unsigned short qh0 = f2bf(qv[0][e]), qh1 = f2bf(qv[1][e]);
            const unsigned short kh0 = f2bf(kv[0][e]), kh1 = f2bf(kv[1][e]);
            *(ushort2*)((char*)QTh + off) = (ushort2){qh0, qh1};
            *(ushort2*)((char*)QTl + off) = (ushort2){f2bf(qv[0][e] - bf2f(qh0)),
                                                      f2bf(qv[1][e] - bf2f(qh1))};
            *(ushort2*)((char*)KTh + off) = (ushort2){kh0, kh1};
            *(ushort2*)((char*)KTl + off) = (ushort2){f2bf(kv[0][e] - bf2f(kh0)),
                                                      f2bf(kv[1][e] - bf2f(kh1))};
        }
        __syncthreads();

        short8 bh[8], bl[8];
#pragma unroll
        for (int nr = 0; nr < 8; ++nr) {
            const int wrow = (nr << 4) + (lane & 15);
            bh[nr] = *(short8*)((char*)KTh + SWZ(wrow, kb));
            bl[nr] = *(short8*)((char*)KTl + SWZ(wrow, kb));
        }
#pragma unroll
        for (int mr = 0; mr < 2; ++mr) {
            const int vrow = (wv << 5) + (mr << 4) + (lane & 15);
            const short8 ah = *(short8*)((char*)QTh + SWZ(vrow, kb));
            const short8 al = *(short8*)((char*)QTl + SWZ(vrow, kb));
#pragma unroll
            for (int nr = 0; nr < 8; ++nr) {
                acc[mr][nr] = __builtin_amdgcn_mfma_f32_16x16x32_bf16(ah, bh[nr], acc[mr][nr], 0, 0, 0);
                acc[mr][nr] = __builtin_amdgcn_mfma_f32_16x16x32_bf16(ah, bl[nr], acc[mr][nr], 0, 0, 0);
                acc[mr][nr] = __builtin_amdgcn_mfma_f32_16x16x32_bf16(al, bh[nr], acc[mr][nr], 0, 0, 0);
            }
        }
        __syncthreads();
    }

    float* Sp = Q + (size_t)bc * HW_;   // in-place: all Q reads completed
    const int r4 = (lane >> 4) << 2;
#pragma unroll
    for (int mr = 0; mr < 2; ++mr) {
#pragma unroll
        for (int nr = 0; nr < 8; ++nr) {
            const f32x4 a = acc[mr][nr];
            const int w = (nr << 4) + (lane & 15);
#pragma unroll
            for (int r = 0; r < 4; ++r) {
                const int v = (wv << 5) + (mr << 4) + r4 + r;
                Sp[(size_t)v * W_ + w] = a[r];
            }
        }
    }
}

// ---------------------------------------------------------------------------
// softmax over batch axis on ST[b][c][v][w]; emits attn^T as bf16 hi/lo
// into pre-swizzled 8KB tiles: tile (b,c,wblk) holds [128 v][32 w] with
// byte layout SWZ(v, (w&31)*2) -> av_mfma copies tiles to LDS linearly.
// ---------------------------------------------------------------------------
__global__ __launch_bounds__(256)
void softmax_pack(const float* __restrict__ S,
                  unsigned short* __restrict__ aH, unsigned short* __restrict__ aL)
{
    const size_t N = (size_t)C_ * HW_;               // 4194304 per batch
    const size_t idx = ((size_t)blockIdx.x * 256 + threadIdx.x) << 2;
    if (idx >= N) return;

    float4 vals[B_];
#pragma unroll
    for (int b = 0; b < B_; ++b) vals[b] = *(const float4*)(S + (size_t)b * N + idx);

    float4 mx = vals[0];
#pragma unroll
    for (int b = 1; b < B_; ++b) {
        mx.x = fmaxf(mx.x, vals[b].x); mx.y = fmaxf(mx.y, vals[b].y);
        mx.z = fmaxf(mx.z, vals[b].z); mx.w = fmaxf(mx.w, vals[b].w);
    }
    float4 sum = {0.f, 0.f, 0.f, 0.f};
#pragma unroll
    for (int b = 0; b < B_; ++b) {
        vals[b].x = expf(vals[b].x - mx.x); sum.x += vals[b].x;
        vals[b].y = expf(vals[b].y - mx.y); sum.y += vals[b].y;
        vals[b].z = expf(vals[b].z - mx.z); sum.z += vals[b].z;
        vals[b].w = expf(vals[b].w - mx.w); sum.w += vals[b].w;
    }
    const float4 inv = {1.f / sum.x, 1.f / sum.y, 1.f / sum.z, 1.f / sum.w};

    const int c = (int)(idx >> 14);
    const int r = (int)(idx & 16383);
    const int v = r >> 7, w = r & 127;
    const size_t tile_byte = ((size_t)(c << 2) + (w >> 5)) * 8192 + SWZ(v, (w & 31) << 1);

#pragma unroll
    for (int b = 0; b < B_; ++b) {
        const float o0 = vals[b].x * inv.x, o1 = vals[b].y * inv.y,
                    o2 = vals[b].z * inv.z, o3 = vals[b].w * inv.w;
        const unsigned short h0 = f2bf(o0), h1 = f2bf(o1),
                             h2 = f2bf(o2), h3 = f2bf(o3);
        char* bh = (char*)(aH + (size_t)b * N) + tile_byte;
        char* bl = (char*)(aL + (size_t)b * N) + tile_byte;
        *(ushort4*)bh = (ushort4){h0, h1, h2, h3};
        *(ushort4*)bl = (ushort4){f2bf(o0 - bf2f(h0)), f2bf(o1 - bf2f(h1)),
                                  f2bf(o2 - bf2f(h2)), f2bf(o3 - bf2f(h3))};
    }
}

// ---------------------------------------------------------------------------
// AV via MFMA bf16x3: per (b,c): O[h][v] = sum_w V[h][w]*attnT[v][w].
// A=V (m=h,k=w, already k-contiguous: convert-only staging);
// B=attn^T tiles (copied LINEARLY to LDS, already swizzled+split).
// O written IN-PLACE over V slice -> out2[b][c][h][v] (reference layout).
// ---------------------------------------------------------------------------
__global__ __launch_bounds__(256)
void av_mfma(float* __restrict__ V,
             const unsigned short* __restrict__ aH,
             const unsigned short* __restrict__ aL)
{
    __shared__ unsigned short Vh[128 * 32], Vl[128 * 32];
    __shared__ unsigned short Ath[128 * 32], Atl[128 * 32];

    const int bc = blockIdx.x;
    float* Vp = V + (size_t)bc * HW_;
    const int t = threadIdx.x, lane = t & 63, wv = t >> 6;
    const int kb = (lane >> 4) << 4;

    const int hrow = t >> 1;           // 0..127
    const int wc   = (t & 1) << 4;     // 0 / 16

    f32x4 acc[2][8];
#pragma unroll
    for (int mr = 0; mr < 2; ++mr)
#pragma unroll
        for (int nr = 0; nr < 8; ++nr)
            acc[mr][nr] = (f32x4){0.f, 0.f, 0.f, 0.f};

    for (int ks = 0; ks < 4; ++ks) {
        const int w0 = ks << 5;
        // stage V[h][w0..w0+31] -> hi/lo swizzled planes
#pragma unroll
        for (int f = 0; f < 4; ++f) {
            const int wl = wc + (f << 2);
            const float4 v4 = *(const float4*)(Vp + (size_t)hrow * W_ + w0 + wl);
            const unsigned short h0 = f2bf(v4.x), h1 = f2bf(v4.y),
                                 h2 = f2bf(v4.z), h3 = f2bf(v4.w);
            const int off = SWZ(hrow, wl << 1);
            *(ushort4*)((char*)Vh + off) = (ushort4){h0, h1, h2, h3};
            *(ushort4*)((char*)Vl + off) = (ushort4){f2bf(v4.x - bf2f(h0)), f2bf(v4.y - bf2f(h1)),
                                                     f2bf(v4.z - bf2f(h2)), f2bf(v4.w - bf2f(h3))};
        }
        // stage attn tiles: linear 16B copies (tiles pre-swizzled by softmax_pack)
        {
            const size_t tb = ((size_t)(bc << 2) + ks) << 12;   // ushort offset (4096/tile... *8192B = <<12 ushorts*2)
            const uint4* gh = (const uint4*)(aH + tb);
            const uint4* gl = (const uint4*)(aL + tb);
            ((uint4*)Ath)[t]       = gh[t];
            ((uint4*)Ath)[t + 256] = gh[t + 256];
            ((uint4*)Atl)[t]       = gl[t];
            ((uint4*)Atl)[t + 256] = gl[t + 256];
        }
        __syncthreads();

        short8 bh[8], bl[8];
#pragma unroll
        for (int nr = 0; nr < 8; ++nr) {
            const int vrow = (nr << 4) + (lane & 15);
            bh[nr] = *(short8*)((char*)Ath + SWZ(vrow, kb));
            bl[nr] = *(short8*)((char*)Atl + SWZ(vrow, kb));
        }
#pragma unroll
        for (int mr = 0; mr < 2; ++mr) {
            const int hr = (wv << 5) + (mr << 4) + (lane & 15);
            const short8 ah = *(short8*)((char*)Vh + SWZ(hr, kb));
            const short8 al = *(short8*)((char*)Vl + SWZ(hr, kb));
#pragma unroll
            for (int nr = 0; nr < 8; ++nr) {
                acc[mr][nr] = __builtin_amdgcn_mfma_f32_16x16x32_bf16(ah, bh[nr], acc[mr][nr], 0, 0, 0);
                acc[mr][nr] = __builtin_amdgcn_mfma_f32_16x16x32_bf16(ah, bl[nr], acc[mr][nr], 0, 0, 0);
                acc[mr][nr] = __builtin_amdgcn_mfma_f32_16x16x32_bf16(al, bh[nr], acc[mr][nr], 0, 0, 0);
            }
        }
        __syncthreads();
    }

    const int r4 = (lane >> 4) << 2;
#pragma unroll
    for (int mr = 0; mr < 2; ++mr) {
#pragma unroll
        for (int nr = 0; nr < 8; ++nr) {
            const f32x4 a = acc[mr][nr];
            const int vcol = (nr << 4) + (lane & 15);
#pragma unroll
            for (int r = 0; r < 4; ++r) {
                const int h = (wv << 5) + (mr << 4) + r4 + r;
                Vp[(size_t)h * W_ + vcol] = a[r];
            }
        }
    }
}

// ---------------------------------------------------------------------------
extern "C" void kernel_launch(void* const* d_in, const int* in_sizes, int n_in,
                              void* d_out, int out_size, void* d_ws, size_t ws_size,
                              hipStream_t stream)
{
    const float* x  = (const float*)d_in[0];
    const float* wk = (const float*)d_in[1];
    const float* bk = (const float*)d_in[2];
    const float* wq = (const float*)d_in[3];
    const float* bq = (const float*)d_in[4];
    const float* wv = (const float*)d_in[5];
    const float* bv = (const float*)d_in[6];
    const float* wo = (const float*)d_in[7];
    const float* bo = (const float*)d_in[8];
    float* out = (float*)d_out;

    const size_t NBUF = (size_t)B_ * PLANE;   // 33554432 elems
    float* kbuf = (float*)d_ws;               // k -> (dead) -> attn hi/lo packed
    float* qbuf = kbuf + NBUF;                // q -> ST (in place)
    float* vbuf = qbuf + NBUF;                // v -> out2 (in place)
    unsigned short* attnH = (unsigned short*)kbuf;          // 33.5M ushorts
    unsigned short* attnL = attnH + NBUF;                   // 33.5M ushorts (= kbuf exactly)

    // fused k/q/v conv via MFMA bf16x3
    const dim3 gKQV(HW_ / 128, C_ / 32, B_);
    conv_mfma<3, 32, false><<<gKQV, 256, 0, stream>>>(
        x, wk, wq, wv, bk, bq, bv, nullptr, kbuf, qbuf, vbuf);

    scores_mfma<<<B_ * C_, 256, 0, stream>>>(kbuf, qbuf);        // qbuf := ST
    softmax_pack<<<4096, 256, 0, stream>>>(qbuf, attnH, attnL);  // kbuf := attn^T hi/lo tiles
    av_mfma<<<B_ * C_, 256, 0, stream>>>(vbuf, attnH, attnL);    // vbuf := out2

    // wo conv + bias + residual via MFMA bf16x3
    const dim3 gWO(HW_ / 128, C_ / 64, B_);
    conv_mfma<1, 64, true><<<gWO, 256, 0, stream>>>(
        vbuf, wo, nullptr, nullptr, bo, nullptr, nullptr, x, out, nullptr, nullptr);
}